// Round 9
// baseline (123.554 us; speedup 1.0000x reference)
//
#include <hip/hip_runtime.h>

// PrimalDualNetwork: 10-iter Chambolle-Pock ROF on 2048x2048 fp32.
// R17: escape the 32-VGPR / LDS-pipe trap. R16 post-mortem: BOTH pipes
// near-saturated (VALU 63%, LDS ~11 ds-inst/unit-iter ~ 26us of the
// 47us); the arg=8 -> 32-VGPR clamp forced sw/ci into LDS, trading
// registers for LDS-pipe cycles. Fix: NT=768 (12-wave blocks), arg=6:
//  - residency law (R9-R16: waves/CU = 4 x arg, block-granular):
//    24 waves = exactly 2 blocks/CU; grid 32x32 = 2 uniform rounds.
//  - VGPR cap 512/6 = 85 -> sw (h4 x2), ci (f32 pairs, no per-iter
//    cvt), own-qv back in REGISTERS (~78 total). ds/unit-iter 11 -> 7.
//  - rrp right-neighbor read: ds_read b64 at +8 (contiguous stride-8,
//    conflict-free) -- kills R16's 4-way-conflict b32 (520K -> <100K).
//  - all LDS addresses = one hoisted base VGPR (tid*8) + compile-time
//    immediates (p*6144 < 64K fits DS offset) -> near-zero addr math.
//  - LDS = sXT16 + sQV + sQH3 = 33.2 KB/block; 2 blocks = 66 KB.
// Tripwires: VGPR=32 => arg=6 clamps too (law wrong); WRITE >> 20 MB
// => spills at ~78 regs; Occ ~38% => only 1 block resident.
// Numerics: identical except ci held fp32 (was fp16 in LDS) -> same or
// slightly better absmax.

namespace {
constexpr int M = 2048, N = 2048;
constexpr float SIGMA     = 1.0f / (7.0f * 0.01f);
constexpr float TAUIS     = 0.01f * (7.0f * 0.01f);  // tau/sigma
constexpr float LT        = 4.0f * 0.01f;
constexpr float INV_DEN   = 1.0f / (1.0f + 4.0f * 0.01f);
constexpr float TAUIS_ID  = TAUIS * INV_DEN;
constexpr float LT_ID     = LT * INV_DEN;
constexpr int TW = 64, TH = 64;     // output tile
constexpr int PC = 88;              // plane cols (12 + 64 + 12)
constexpr int PR = 84;              // plane rows (10 + 64 + 10)
constexpr int UPR = 22;             // h4 units per row == PC/4
constexpr int PROC = 83;            // rows 0..82 processed (83 read-only)
constexpr int NU = PROC * UPR;      // 1826
constexpr int NT = 768;             // 12 waves
constexpr int NPASS = 3;            // 3*768=2304 >= PR*UPR=1848
constexpr int GY = M / TH;          // 32  (exact: no partial tiles)
} // namespace

typedef _Float16 h4 __attribute__((ext_vector_type(4)));
typedef float    f2 __attribute__((ext_vector_type(2)));
typedef unsigned uint32;

__device__ inline h4 h4splat(float v) {
    _Float16 s = (_Float16)v;
    return (h4){s, s, s, s};
}
__device__ inline int imax(int a, int b) { return a > b ? a : b; }
__device__ inline uint32 abit(uint32 hi, uint32 lo) {
    return __builtin_amdgcn_alignbit(hi, lo, 16);
}
__device__ inline h4 clamp1(h4 v) {
    return __builtin_elementwise_min(
               __builtin_elementwise_max(v, h4splat(-1.f)), h4splat(1.f));
}

__global__ __launch_bounds__(NT, 6) void pd_fused(
    const float* __restrict__ img, float* __restrict__ out,
    const float* __restrict__ w1p, const float* __restrict__ w2p)
{
    __shared__ __align__(16) _Float16 sXT16[PR * PC];  // 14784 B (xt, fp16)
    __shared__ __align__(16) _Float16 sQV[PR * PC];    // 14784 B
    __shared__ __align__(16) _Float16 sQH3[1832];      //  3664 B (qH[3]/unit)

    const int tid  = threadIdx.x;
    const int c0 = blockIdx.x * TW, r0 = blockIdx.y * TH;
    const int gr0 = r0 - 10, gc0 = c0 - 12;
    const float w1 = w1p[0], w2 = w2p[0];

    // hoisted LDS byte bases (loop-invariant; p-offsets fold into imm)
    char* bXT8 = (char*)sXT16 + tid * 8;
    char* bQV8 = (char*)sQV   + tid * 8;
    char* bQ3  = (char*)sQH3  + tid * 2;
    const char* bQVu0 = (char*)sQV + (tid >= UPR ? tid - UPR : tid) * 8;
    const int   q3o0  = imax(tid - 1, 0);

    // cone deactivation threshold per pass (active iff rem >= d)
    int dth_[NPASS];
    #pragma unroll
    for (int p = 0; p < NPASS; ++p) {
        int u = tid + p * NT;
        int li = u / UPR, lc = (u - li * UPR) * 4;
        int d = imax(imax(9 - li, li - (TH + 9)), imax(8 - lc, lc - 75));
        d = imax(d, 0);
        if (u >= NU) d = 100;
        dth_[p] = d;
    }

    // ---- stage img -> sXT16 (fp16; 0 outside image) ----
    #pragma unroll
    for (int p = 0; p < NPASS; ++p) {
        int su = tid + p * NT;
        if (su < PR * UPR) {
            int li = su / UPR, uj = su - li * UPR;
            int gi = gr0 + li, gj = gc0 + uj * 4;
            float4 v = make_float4(0.f, 0.f, 0.f, 0.f);
            if ((unsigned)gi < (unsigned)M && (unsigned)gj <= (unsigned)(N - 4))
                v = *(const float4*)&img[(size_t)gi * N + gj];
            h4 h; h[0] = (_Float16)v.x; h[1] = (_Float16)v.y;
                  h[2] = (_Float16)v.z; h[3] = (_Float16)v.w;
            *(h4*)(bXT8 + p * 6144) = h;
        }
    }
    __syncthreads();

    // register state (~78 VGPR budget 85): x fp32 pairs, ci fp32 pairs,
    // xt/y/q/sw/qv packed fp16
    f2 xr2[NPASS][2], ci2[NPASS][2];
    h4 xt16[NPASS], yh[NPASS], yv[NPASS], qH[NPASS],
       swh[NPASS], swv[NPASS], qvr[NPASS];

    // ---- init (== dual(0)): sigma*w -> regs, ci -> regs, y0, q0 ----
    #pragma unroll
    for (int p = 0; p < NPASS; ++p) {
        int u = tid + p * NT;
        if (u < NU) {
            int li = u / UPR;
            int gi = gr0 + li, gjb = gc0 + (u - li * UPR) * 4;
            const char* bx = bXT8 + p * 6144;
            h4 c16 = *(const h4*)bx;
            uint2 rr = *(const uint2*)(bx + 8);
            h4 dn = *(const h4*)(bx + 176);          // +PC halves = +176 B
            uint2 xu = __builtin_bit_cast(uint2, c16);
            h4 xsh = __builtin_bit_cast(h4,
                         make_uint2(abit(xu.y, xu.x), abit(rr.x, xu.y)));
            bool rok = (unsigned)gi < (unsigned)M;
            bool vok = rok && (gi < M - 1);
            h4 qv;
            #pragma unroll
            for (int l = 0; l < 4; ++l) {
                int gj = gjb + l;
                bool cok = (unsigned)gj < (unsigned)N;
                bool hok = rok && cok && (gj < N - 1);
                bool vk  = vok && cok;
                float xf  = (float)c16[l];
                float ghf = hok ? (float)xsh[l] - xf : 0.f;
                float gvf = vk  ? (float)dn[l]  - xf : 0.f;
                float wh = fmaf(w2, __expf(-fabsf(ghf)), w1);
                float wv = fmaf(w2, __expf(-fabsf(gvf)), w1);
                float y0h = fminf(fmaxf(ghf * fmaf(SIGMA, wh, 1.f), -1.f), 1.f);
                float y0v = fminf(fmaxf(gvf * fmaf(SIGMA, wv, 1.f), -1.f), 1.f);
                float sh = hok ? SIGMA * wh : 0.f;
                float sv = vk  ? SIGMA * wv : 0.f;
                yh[p][l]  = (_Float16)y0h;  yv[p][l] = (_Float16)y0v;
                swh[p][l] = (_Float16)sh;   swv[p][l] = (_Float16)sv;
                qH[p][l]  = (_Float16)(sh * y0h);
                qv[l]     = (_Float16)(sv * y0v);
                ci2[p][l >> 1][l & 1] = LT_ID * xf;
                xr2[p][l >> 1][l & 1] = xf;
            }
            xt16[p] = c16;
            qvr[p]  = qv;
            *(h4*)(bQV8 + p * 6144) = qv;
            *(_Float16*)(bQ3 + p * 1536) = qH[p][3];
        }
    }
    __syncthreads();

    // ---- dual(t>=1): y = clamp(y + sw*grad16(xt)); q = sw*y
    //      (sw/xt/y in regs; only neighbor xt + q-writes touch LDS) ----
    auto dual = [&](int rem) {
        #pragma unroll
        for (int p = 0; p < NPASS; ++p) {
            if (rem >= dth_[p]) {
                const char* bx = bXT8 + p * 6144;
                uint2 rr = *(const uint2*)(bx + 8);      // stride-8: no conflict
                h4 dn = *(const h4*)(bx + 176);
                uint2 xu = __builtin_bit_cast(uint2, xt16[p]);
                h4 xsh = __builtin_bit_cast(h4,
                             make_uint2(abit(xu.y, xu.x), abit(rr.x, xu.y)));
                h4 ghh = xsh - xt16[p];              // v_pk_sub_f16
                h4 gvh = dn  - xt16[p];
                h4 nh = clamp1(yh[p] + swh[p] * ghh);  // sw=0 masks borders
                h4 nv = clamp1(yv[p] + swv[p] * gvh);
                yh[p] = nh; yv[p] = nv;
                h4 qh = swh[p] * nh;                 // q = sigma*w*y
                h4 qv = swv[p] * nv;
                qH[p] = qh; qvr[p] = qv;
                *(h4*)(bQV8 + p * 6144) = qv;
                *(_Float16*)(bQ3 + p * 1536) = qh[3];
            }
        }
    };

    // ---- primal: xn = fma(INV_DEN, xo, fma(TAUIS_ID, dv, ci)) packed;
    //      xt = 1.5xn - 0.5xo. own-qv/ci from regs; qvu/qhl from LDS.
    //      last: store fp32 to global, skip LDS. ----
    const f2 kID  = {INV_DEN,  INV_DEN};
    const f2 kTS  = {TAUIS_ID, TAUIS_ID};
    const f2 k15  = {1.5f, 1.5f};
    const f2 km05 = {-0.5f, -0.5f};
    auto primal = [&](int rem, bool last) {
        #pragma unroll
        for (int p = 0; p < NPASS; ++p) {
            if (rem >= dth_[p]) {
                h4 qvu = (p == 0) ? *(const h4*)bQVu0
                                  : *(const h4*)(bQV8 + p * 6144 - 176);
                uint32 qhl = (p == 0)
                    ? *(const unsigned short*)&sQH3[q3o0]
                    : *(const unsigned short*)(bQ3 + p * 1536 - 2);
                uint2 qu = __builtin_bit_cast(uint2, qH[p]);
                h4 qsh = __builtin_bit_cast(h4,
                             make_uint2(abit(qu.x, qhl << 16), abit(qu.y, qu.x)));
                h4 dvg = (qH[p] - qsh) + (qvr[p] - qvu);   // v_pk_sub/add_f16
                f2 dv0 = {(float)dvg[0], (float)dvg[1]};
                f2 dv1 = {(float)dvg[2], (float)dvg[3]};
                f2 xo0 = xr2[p][0], xo1 = xr2[p][1];
                f2 xn0 = __builtin_elementwise_fma(kID, xo0,
                             __builtin_elementwise_fma(kTS, dv0, ci2[p][0]));
                f2 xn1 = __builtin_elementwise_fma(kID, xo1,
                             __builtin_elementwise_fma(kTS, dv1, ci2[p][1]));
                xr2[p][0] = xn0; xr2[p][1] = xn1;
                f2 xt0 = __builtin_elementwise_fma(k15, xn0, xo0 * km05);
                f2 xt1 = __builtin_elementwise_fma(k15, xn1, xo1 * km05);
                if (!last) {
                    h4 nx; nx[0] = (_Float16)xt0[0]; nx[1] = (_Float16)xt0[1];
                           nx[2] = (_Float16)xt1[0]; nx[3] = (_Float16)xt1[1];
                    xt16[p] = nx;
                    *(h4*)(bXT8 + p * 6144) = nx;
                } else {
                    int u = tid + p * NT;
                    int li = u / UPR, uj = u - li * UPR;
                    int gi = gr0 + li;
                    if (li >= 10 && uj >= 3 && uj <= 18 && gi < M) {
                        *(float4*)&out[(size_t)gi * N + (gc0 + uj * 4)] =
                            make_float4(xt0[0], xt0[1], xt1[0], xt1[1]);
                    }
                }
            }
        }
    };

    primal(9, false);          // t=0 (dual(0) fused into init)
    __syncthreads();
    #pragma unroll 1
    for (int t = 1; t < 10; ++t) {
        int rem = 9 - t;
        dual(rem);
        __syncthreads();
        primal(rem, t == 9);
        __syncthreads();
    }
}

extern "C" void kernel_launch(void* const* d_in, const int* in_sizes, int n_in,
                              void* d_out, int out_size, void* d_ws, size_t ws_size,
                              hipStream_t stream)
{
    const float* img = (const float*)d_in[0];
    const float* w1  = (const float*)d_in[1];
    const float* w2  = (const float*)d_in[2];
    float* out = (float*)d_out;

    dim3 grid(N / TW, GY);   // 32 x 32 = 1024 blocks = 2/CU x 2 rounds
    pd_fused<<<grid, NT, 0, stream>>>(img, out, w1, w2);
}

// Round 10
// 112.971 us; speedup vs baseline: 1.0937x; 1.0937x over previous
//
#include <hip/hip_runtime.h>

// PrimalDualNetwork: 10-iter Chambolle-Pock ROF on 2048x2048 fp32.
// R18 = R16 numerics at h8 granularity: one thread owns 8 columns
// (16B), NPASS=1. R17 post-mortem: arg=6 relaxation failed (VGPR 40,
// 113 MB spills) -- arg=8/NT=1024 is the only full-residency config
// and it pins 32 VGPR. R16 is both-pipes-saturated; the remaining
// lever is per-element issue count:
//  - unit 4->8 halves: DS insts per elem HALVED (b64->b128, same
//    bytes), alignbit chains/guards/branches per elem halved, 913
//    units <= 1024 threads -> NPASS=1 (no p loops).
//  - live-across-barrier state unchanged (~24 dwords: xr 8, xt 4,
//    yh/yv 8, qH 4) -> same 32-VGPR regime, mild hidden spills.
//  - all planes at 16B lane stride (conflict-free b128); single 8-way
//    access = 4B right-neighbor read, 1x/unit.
//  - one packed LDS segment, planes at compile-time offsets < 64K
//    (DS-imm foldable): 75.8 KB -> 2 blocks/CU at arg=8.
// Tripwires: dur >= 46 => barrier-bound -> restructure phases;
// WRITE >> 30 MB => spills too big. absmax expected exactly 0.00390625.

namespace {
constexpr int M = 2048, N = 2048;
constexpr float SIGMA     = 1.0f / (7.0f * 0.01f);
constexpr float TAUIS     = 0.01f * (7.0f * 0.01f);  // tau/sigma
constexpr float LT        = 4.0f * 0.01f;
constexpr float INV_DEN   = 1.0f / (1.0f + 4.0f * 0.01f);
constexpr float TAUIS_ID  = TAUIS * INV_DEN;
constexpr float LT_ID     = LT * INV_DEN;
constexpr int TW = 64, TH = 64;     // output tile
constexpr int PC = 88;              // plane cols (12 + 64 + 12)
constexpr int PR = 84;              // plane rows (10 + 64 + 10)
constexpr int UPR = 11;             // h8 units per row == PC/8
constexpr int PROC = 83;            // rows 0..82 processed (83 read-only)
constexpr int NU = PROC * UPR;      // 913
constexpr int NS = PR * UPR;        // 924 staged units
constexpr int NT = 1024;            // 16 waves, NPASS = 1
constexpr int GY = M / TH;          // 32  (exact: no partial tiles)
// packed LDS segment (byte offsets; all < 64K -> DS-imm foldable)
constexpr int OQ7 = 0;              // 924 x 2 B  = 1848 -> pad 1856
constexpr int OXT = 1856;           // xt plane, 14784 B
constexpr int OQV = OXT + 14784;    // 16640
constexpr int OCI = OQV + 14784;    // 31424  (LT_ID * img, fp16)
constexpr int OSH = OCI + 14784;    // 46208  (sigma*w horizontal)
constexpr int OSV = OSH + 14784;    // 60992  (sigma*w vertical)
constexpr int LDSZ = OSV + 14784;   // 75776 B
} // namespace

typedef _Float16 h8 __attribute__((ext_vector_type(8)));
typedef float    f2 __attribute__((ext_vector_type(2)));
typedef unsigned uint32;

__device__ inline h8 h8splat(float v) {
    _Float16 s = (_Float16)v;
    return (h8){s, s, s, s, s, s, s, s};
}
__device__ inline int imax(int a, int b) { return a > b ? a : b; }
__device__ inline uint32 abit(uint32 hi, uint32 lo) {
    return __builtin_amdgcn_alignbit(hi, lo, 16);
}
__device__ inline h8 clamp1(h8 v) {
    return __builtin_elementwise_min(
               __builtin_elementwise_max(v, h8splat(-1.f)), h8splat(1.f));
}

__global__ __launch_bounds__(NT, 8) void pd_fused(
    const float* __restrict__ img, float* __restrict__ out,
    const float* __restrict__ w1p, const float* __restrict__ w2p)
{
    __shared__ __align__(16) char sB[LDSZ];

    const int tid = threadIdx.x;
    const int c0 = blockIdx.x * TW, r0 = blockIdx.y * TH;
    const int gr0 = r0 - 10, gc0 = c0 - 12;
    const float w1 = w1p[0], w2 = w2p[0];

    // hoisted LDS byte bases (plane selection via compile-time imm)
    char* b16 = sB + tid * 16;
    char* bQ7 = sB + OQ7 + tid * 2;
    const char* bQVu = b16 + OQV - (tid >= UPR ? 176 : 0); // row-0: own (junk ok)
    const char* bQ7l = sB + OQ7 + imax(tid - 1, 0) * 2;    // left q carry

    // cone deactivation threshold (active iff rem >= d)
    int dth;
    {
        int li = tid / UPR, lc = (tid - li * UPR) * 8;
        int d = imax(imax(9 - li, li - (TH + 9)), imax(4 - lc, lc - 75));
        d = imax(d, 0);
        if (tid >= NU) d = 100;
        dth = d;
    }

    // ---- stage img -> xt plane (fp16; 0 outside image) ----
    if (tid < NS) {
        int li = tid / UPR, uj = tid - li * UPR;
        int gi = gr0 + li, gj0 = gc0 + uj * 8;
        float4 v0 = make_float4(0.f, 0.f, 0.f, 0.f);
        float4 v1 = make_float4(0.f, 0.f, 0.f, 0.f);
        bool rok = (unsigned)gi < (unsigned)M;
        if (rok && (unsigned)gj0 <= (unsigned)(N - 4))
            v0 = *(const float4*)&img[(size_t)gi * N + gj0];
        if (rok && (unsigned)(gj0 + 4) <= (unsigned)(N - 4))
            v1 = *(const float4*)&img[(size_t)gi * N + gj0 + 4];
        h8 h;
        h[0] = (_Float16)v0.x; h[1] = (_Float16)v0.y;
        h[2] = (_Float16)v0.z; h[3] = (_Float16)v0.w;
        h[4] = (_Float16)v1.x; h[5] = (_Float16)v1.y;
        h[6] = (_Float16)v1.z; h[7] = (_Float16)v1.w;
        *(h8*)(b16 + OXT) = h;
    }
    __syncthreads();

    // register state (~24 dwords live across barriers)
    f2 xr2[4];
    h8 xt16, yh, yv, qH;

    // ---- init (== dual(0)): sw/ci -> LDS planes, y0, q0 ----
    if (tid < NU) {
        int li = tid / UPR;
        int gi = gr0 + li, gjb = gc0 + (tid - li * UPR) * 8;
        h8 c16 = *(const h8*)(b16 + OXT);
        uint32 rr = *(const uint32*)(b16 + OXT + 16);
        h8 dn = *(const h8*)(b16 + OXT + 176);
        uint4 xu = __builtin_bit_cast(uint4, c16);
        h8 xsh = __builtin_bit_cast(h8,
                     make_uint4(abit(xu.y, xu.x), abit(xu.z, xu.y),
                                abit(xu.w, xu.z), abit(rr, xu.w)));
        bool rok = (unsigned)gi < (unsigned)M;
        bool vok = rok && (gi < M - 1);
        h8 qv, swh, swv, civ;
        #pragma unroll
        for (int l = 0; l < 8; ++l) {
            int gj = gjb + l;
            bool cok = (unsigned)gj < (unsigned)N;
            bool hok = rok && cok && (gj < N - 1);
            bool vk  = vok && cok;
            float xf  = (float)c16[l];
            float ghf = hok ? (float)xsh[l] - xf : 0.f;
            float gvf = vk  ? (float)dn[l]  - xf : 0.f;
            float wh = fmaf(w2, __expf(-fabsf(ghf)), w1);
            float wv = fmaf(w2, __expf(-fabsf(gvf)), w1);
            float y0h = fminf(fmaxf(ghf * fmaf(SIGMA, wh, 1.f), -1.f), 1.f);
            float y0v = fminf(fmaxf(gvf * fmaf(SIGMA, wv, 1.f), -1.f), 1.f);
            float sh = hok ? SIGMA * wh : 0.f;
            float sv = vk  ? SIGMA * wv : 0.f;
            yh[l]  = (_Float16)y0h;  yv[l] = (_Float16)y0v;
            swh[l] = (_Float16)sh;   swv[l] = (_Float16)sv;
            qH[l]  = (_Float16)(sh * y0h);
            qv[l]  = (_Float16)(sv * y0v);
            civ[l] = (_Float16)(LT_ID * xf);
            xr2[l >> 1][l & 1] = xf;
        }
        xt16 = c16;
        *(h8*)(b16 + OSH) = swh;
        *(h8*)(b16 + OSV) = swv;
        *(h8*)(b16 + OCI) = civ;
        *(h8*)(b16 + OQV) = qv;
        *(_Float16*)bQ7 = qH[7];
    }
    __syncthreads();

    // ---- dual(t>=1): y = clamp(y + sw*grad16(xt)); q = sw*y ----
    auto dual = [&](int rem) {
        if (rem >= dth) {
            uint32 rr = *(const uint32*)(b16 + OXT + 16);  // 8-way, 1x/unit
            h8 dn  = *(const h8*)(b16 + OXT + 176);
            h8 swh = *(const h8*)(b16 + OSH);
            h8 swv = *(const h8*)(b16 + OSV);
            uint4 xu = __builtin_bit_cast(uint4, xt16);
            h8 xsh = __builtin_bit_cast(h8,
                         make_uint4(abit(xu.y, xu.x), abit(xu.z, xu.y),
                                    abit(xu.w, xu.z), abit(rr, xu.w)));
            h8 ghh = xsh - xt16;                 // v_pk_sub_f16 x4
            h8 gvh = dn  - xt16;
            h8 nh = clamp1(yh + swh * ghh);      // sw=0 masks borders
            h8 nv = clamp1(yv + swv * gvh);
            yh = nh; yv = nv;
            h8 qh = swh * nh;                    // q = sigma*w*y
            h8 qv = swv * nv;
            qH = qh;
            *(h8*)(b16 + OQV) = qv;
            *(_Float16*)bQ7 = qh[7];
        }
    };

    // ---- primal: xn = fma(INV_DEN, xo, fma(TAUIS_ID, dv, ci)) packed;
    //      xt = 1.5xn - 0.5xo. last: store fp32 to global, skip LDS. ----
    const f2 kID  = {INV_DEN,  INV_DEN};
    const f2 kTS  = {TAUIS_ID, TAUIS_ID};
    const f2 k15  = {1.5f, 1.5f};
    const f2 km05 = {-0.5f, -0.5f};
    auto primal = [&](int rem, bool last) {
        if (rem >= dth) {
            h8 qvu = *(const h8*)bQVu;
            h8 qvo = *(const h8*)(b16 + OQV);
            h8 civ = *(const h8*)(b16 + OCI);
            uint32 qhl = *(const unsigned short*)bQ7l;
            uint4 qu = __builtin_bit_cast(uint4, qH);
            h8 qsh = __builtin_bit_cast(h8,
                         make_uint4(abit(qu.x, qhl << 16), abit(qu.y, qu.x),
                                    abit(qu.z, qu.y),      abit(qu.w, qu.z)));
            h8 dvg = (qH - qsh) + (qvo - qvu);   // v_pk_sub/add_f16
            f2 xtv[4];
            #pragma unroll
            for (int i = 0; i < 4; ++i) {
                f2 dv = {(float)dvg[2 * i], (float)dvg[2 * i + 1]};
                f2 ci = {(float)civ[2 * i], (float)civ[2 * i + 1]};
                f2 xo = xr2[i];
                f2 xn = __builtin_elementwise_fma(kID, xo,
                            __builtin_elementwise_fma(kTS, dv, ci));
                xr2[i] = xn;
                xtv[i] = __builtin_elementwise_fma(k15, xn, xo * km05);
            }
            if (!last) {
                h8 nx;
                #pragma unroll
                for (int i = 0; i < 4; ++i) {
                    nx[2 * i]     = (_Float16)xtv[i][0];
                    nx[2 * i + 1] = (_Float16)xtv[i][1];
                }
                xt16 = nx;
                *(h8*)(b16 + OXT) = nx;
            } else {
                int li = tid / UPR, uj = tid - li * UPR;
                int gi = gr0 + li, gj0 = gc0 + uj * 8;
                if (li >= 10) {          // li<=73 & uj in [1,9] via cone guard
                    if (uj >= 2)         // cols gj0..gj0+3 inside output
                        *(float4*)&out[(size_t)gi * N + gj0] =
                            make_float4(xtv[0][0], xtv[0][1], xtv[1][0], xtv[1][1]);
                    if (uj <= 8)         // cols gj0+4..gj0+7 inside output
                        *(float4*)&out[(size_t)gi * N + gj0 + 4] =
                            make_float4(xtv[2][0], xtv[2][1], xtv[3][0], xtv[3][1]);
                }
            }
        }
    };

    primal(9, false);          // t=0 (dual(0) fused into init)
    __syncthreads();
    #pragma unroll 1
    for (int t = 1; t < 10; ++t) {
        int rem = 9 - t;
        dual(rem);
        __syncthreads();
        primal(rem, t == 9);
        __syncthreads();
    }
}

extern "C" void kernel_launch(void* const* d_in, const int* in_sizes, int n_in,
                              void* d_out, int out_size, void* d_ws, size_t ws_size,
                              hipStream_t stream)
{
    const float* img = (const float*)d_in[0];
    const float* w1  = (const float*)d_in[1];
    const float* w2  = (const float*)d_in[2];
    float* out = (float*)d_out;

    dim3 grid(N / TW, GY);   // 32 x 32 = 1024 blocks = 2/CU x 2 rounds
    pd_fused<<<grid, NT, 0, stream>>>(img, out, w1, w2);
}

// Round 12
// 106.071 us; speedup vs baseline: 1.1648x; 1.0651x over previous
//
#include <hip/hip_runtime.h>

// PrimalDualNetwork: 10-iter Chambolle-Pock ROF on 2048x2048 fp32.
// R19b = R19 with the cvt_pkrtz type fix (builtin returns __fp16x2,
// not _Float16x2 -> capture native type, bit_cast to uint32).
// R19 = R16 (tile 64x64, NT=1024, NPASS=2, arg=8, 32-VGPR regime,
// LDS planes, h4 units) + targeted issue diet. R18 post-mortem: h8
// blew the 32-VGPR temp budget -> LDS re-reads + remat (VALU time UP);
// h4 is the right width. R16 profile: VALU ~30us, LDS-pipe ~26us
// (11 ds/unit-iter). Cuts, zero structural change:
//  1. swh/swv merged into ONE interleaved plane, read as a single
//     ds_read_b128 in dual (-1 ds inst; same bytes).
//  2. primal correction s = TAUIS_ID*dvg + ci as ONE packed-f16 fma
//     (s <= 0.073, fp16 err ~3e-5/iter -> ~7e-4 accumulated; budget
//     0.0177). Replaces 8 f16->f32 cvts with 4.
//  3. xt repack via v_cvt_pkrtz (2 ops instead of 4 cvt+pack). RTZ
//     rounding: tiny extra err, covered by budget.
// Tripwire: dur >= 46 => issue-diet exhausted; residual is
// barrier/latency-structural. absmax expected <= 0.006.

namespace {
constexpr int M = 2048, N = 2048;
constexpr float SIGMA     = 1.0f / (7.0f * 0.01f);
constexpr float TAUIS     = 0.01f * (7.0f * 0.01f);  // tau/sigma
constexpr float LT        = 4.0f * 0.01f;
constexpr float INV_DEN   = 1.0f / (1.0f + 4.0f * 0.01f);
constexpr float TAUIS_ID  = TAUIS * INV_DEN;
constexpr float LT_ID     = LT * INV_DEN;
constexpr int TW = 64, TH = 64;     // output tile
constexpr int PC = 88;              // plane cols (12 + 64 + 12)
constexpr int PR = 84;              // plane rows (10 + 64 + 10)
constexpr int UPR = 22;             // h4 units per row == PC/4
constexpr int PROC = 83;            // rows 0..82 processed (83 read-only)
constexpr int NU = PROC * UPR;      // 1826
constexpr int NT = 1024;            // 16 waves
constexpr int NPASS = 2;            // 2*1024 >= NU (and >= PR*UPR=1848)
constexpr int GY = M / TH;          // 32  (exact: no partial tiles)
} // namespace

typedef _Float16 h4 __attribute__((ext_vector_type(4)));
typedef float    f2 __attribute__((ext_vector_type(2)));
typedef unsigned uint32;

__device__ inline h4 h4splat(float v) {
    _Float16 s = (_Float16)v;
    return (h4){s, s, s, s};
}
__device__ inline int imax(int a, int b) { return a > b ? a : b; }
__device__ inline uint32 abit(uint32 hi, uint32 lo) {
    return __builtin_amdgcn_alignbit(hi, lo, 16);
}
__device__ inline h4 clamp1(h4 v) {
    return __builtin_elementwise_min(
               __builtin_elementwise_max(v, h4splat(-1.f)), h4splat(1.f));
}
// packed f32->f16 (RTZ); builtin returns __fp16x2 -> pass through uint32
__device__ inline uint32 pkrtz(float a, float b) {
    return __builtin_bit_cast(uint32, __builtin_amdgcn_cvt_pkrtz(a, b));
}

__global__ __launch_bounds__(NT, 8) void pd_fused(
    const float* __restrict__ img, float* __restrict__ out,
    const float* __restrict__ w1p, const float* __restrict__ w2p)
{
    __shared__ __align__(16) _Float16 sXT16[PR * PC];   // 14784 B (xt, fp16)
    __shared__ __align__(16) _Float16 sQV[PR * PC];     // 14784 B
    __shared__ __align__(16) _Float16 sCI[PR * PC];     // 14784 B (LT_ID*img)
    __shared__ __align__(16) _Float16 sSW[2 * PR * PC]; // 29568 B (swh|swv interleaved per unit)
    __shared__ __align__(16) _Float16 sQH3[1840];       //  3680 B (qH[3]/unit)

    const int tid  = threadIdx.x;
    const int c0 = blockIdx.x * TW, r0 = blockIdx.y * TH;
    const int gr0 = r0 - 10, gc0 = c0 - 12;
    const float w1 = w1p[0], w2 = w2p[0];

    // cone deactivation threshold per pass (active iff rem >= d)
    int dth_[NPASS];
    #pragma unroll
    for (int p = 0; p < NPASS; ++p) {
        int u = tid + p * NT;
        int li = u / UPR, lc = (u - li * UPR) * 4;
        int d = imax(imax(9 - li, li - (TH + 9)), imax(8 - lc, lc - 75));
        d = imax(d, 0);
        if (u >= NU) d = 100;
        dth_[p] = d;
    }

    // ---- stage img -> sXT16 (fp16; 0 outside image) ----
    #pragma unroll
    for (int p = 0; p < NPASS; ++p) {
        int su = tid + p * NT;
        if (su < PR * UPR) {
            int li = su / UPR, uj = su - li * UPR;
            int gi = gr0 + li, gj = gc0 + uj * 4;
            float4 v = make_float4(0.f, 0.f, 0.f, 0.f);
            if ((unsigned)gi < (unsigned)M && (unsigned)gj <= (unsigned)(N - 4))
                v = *(const float4*)&img[(size_t)gi * N + gj];
            h4 h; h[0] = (_Float16)v.x; h[1] = (_Float16)v.y;
                  h[2] = (_Float16)v.z; h[3] = (_Float16)v.w;
            *(h4*)&sXT16[su * 4] = h;
        }
    }
    __syncthreads();

    // register state (fits 32 VGPR): x fp32 pairs, xt/y/q packed fp16
    f2 xr2[NPASS][2];
    h4 xt16[NPASS], yh[NPASS], yv[NPASS], qH[NPASS];

    // ---- init (== dual(0)): sigma*w -> sSW, ci -> sCI, y0, q0 ----
    #pragma unroll
    for (int p = 0; p < NPASS; ++p) {
        int u = tid + p * NT;
        if (u < NU) {
            int bF = u * 4;
            int li = u / UPR;
            int gi = gr0 + li, gjb = gc0 + (u - li * UPR) * 4;
            h4 c16 = *(const h4*)&sXT16[bF];
            uint32 rrp = *(const uint32*)&sXT16[bF + 4];
            h4 dn = *(const h4*)&sXT16[bF + PC];
            uint2 xu = __builtin_bit_cast(uint2, c16);
            h4 xsh = __builtin_bit_cast(h4,
                         make_uint2(abit(xu.y, xu.x), abit(rrp, xu.y)));
            bool rok = (unsigned)gi < (unsigned)M;
            bool vok = rok && (gi < M - 1);
            h4 qv, swhv, swvv, civ;
            #pragma unroll
            for (int l = 0; l < 4; ++l) {
                int gj = gjb + l;
                bool cok = (unsigned)gj < (unsigned)N;
                bool hok = rok && cok && (gj < N - 1);
                bool vk  = vok && cok;
                float xf  = (float)c16[l];
                float ghf = hok ? (float)xsh[l] - xf : 0.f;
                float gvf = vk  ? (float)dn[l]  - xf : 0.f;
                float wh = fmaf(w2, __expf(-fabsf(ghf)), w1);
                float wv = fmaf(w2, __expf(-fabsf(gvf)), w1);
                float y0h = fminf(fmaxf(ghf * fmaf(SIGMA, wh, 1.f), -1.f), 1.f);
                float y0v = fminf(fmaxf(gvf * fmaf(SIGMA, wv, 1.f), -1.f), 1.f);
                float sh = hok ? SIGMA * wh : 0.f;
                float sv = vk  ? SIGMA * wv : 0.f;
                yh[p][l]   = (_Float16)y0h;  yv[p][l] = (_Float16)y0v;
                swhv[l]    = (_Float16)sh;   swvv[l]  = (_Float16)sv;
                qH[p][l]   = (_Float16)(sh * y0h);
                qv[l]      = (_Float16)(sv * y0v);
                civ[l]     = (_Float16)(LT_ID * xf);
                xr2[p][l >> 1][l & 1] = xf;
            }
            xt16[p] = c16;
            *(h4*)&sSW[bF * 2]     = swhv;   // unit u: halves [8u, 8u+4)
            *(h4*)&sSW[bF * 2 + 4] = swvv;   //          halves [8u+4, 8u+8)
            *(h4*)&sCI[bF]  = civ;
            *(h4*)&sQV[bF]  = qv;
            sQH3[u] = qH[p][3];
        }
    }
    __syncthreads();

    // ---- dual(t>=1): y = clamp(y + sw*grad16(xt)); q = sw*y
    //      sw via ONE b128 read of the interleaved plane ----
    auto dual = [&](int rem) {
        #pragma unroll
        for (int p = 0; p < NPASS; ++p) {
            if (rem >= dth_[p]) {
                int bF = (tid + p * NT) * 4;
                uint32 rrp = *(const uint32*)&sXT16[bF + 4];
                h4 dn  = *(const h4*)&sXT16[bF + PC];
                uint4 swp = *(const uint4*)&sSW[bF * 2];     // b128
                h4 swh = __builtin_bit_cast(h4, make_uint2(swp.x, swp.y));
                h4 swv = __builtin_bit_cast(h4, make_uint2(swp.z, swp.w));
                uint2 xu = __builtin_bit_cast(uint2, xt16[p]);
                h4 xsh = __builtin_bit_cast(h4,
                             make_uint2(abit(xu.y, xu.x), abit(rrp, xu.y)));
                h4 ghh = xsh - xt16[p];              // v_pk_sub_f16
                h4 gvh = dn  - xt16[p];
                h4 nh = clamp1(yh[p] + swh * ghh);   // sw=0 masks borders
                h4 nv = clamp1(yv[p] + swv * gvh);
                yh[p] = nh; yv[p] = nv;
                h4 qh = swh * nh;                    // q = sigma*w*y
                h4 qv = swv * nv;
                qH[p] = qh;
                *(h4*)&sQV[bF] = qv;
                sQH3[bF >> 2] = qh[3];
            }
        }
    };

    // ---- primal: s16 = TAUIS_ID*dvg + ci (packed f16);
    //      xn = fma(INV_DEN, xo, cvt(s16)); xt = 1.5xn - 0.5xo;
    //      repack via v_cvt_pkrtz. last: fp32 store, skip LDS. ----
    const f2 kID  = {INV_DEN,  INV_DEN};
    const f2 k15  = {1.5f, 1.5f};
    const f2 km05 = {-0.5f, -0.5f};
    const h4 kTS16 = h4splat(TAUIS_ID);
    auto primal = [&](int rem, bool last) {
        #pragma unroll
        for (int p = 0; p < NPASS; ++p) {
            if (rem >= dth_[p]) {
                int u = tid + p * NT, bF = u * 4;
                int bu = (bF >= UPR * 4) ? bF - PC : bF;  // row-0 junk tolerated
                h4 qvu = *(const h4*)&sQV[bu];
                h4 qv  = *(const h4*)&sQV[bF];
                h4 civ = *(const h4*)&sCI[bF];
                uint32 qhl = *(const unsigned short*)&sQH3[imax(u - 1, 0)];
                uint2 qu = __builtin_bit_cast(uint2, qH[p]);
                h4 qsh = __builtin_bit_cast(h4,
                             make_uint2(abit(qu.x, qhl << 16), abit(qu.y, qu.x)));
                h4 dvg = (qH[p] - qsh) + (qv - qvu);     // v_pk_sub/add_f16
                h4 s16 = kTS16 * dvg + civ;              // packed f16 fma
                f2 s0 = {(float)s16[0], (float)s16[1]};
                f2 s1 = {(float)s16[2], (float)s16[3]};
                f2 xo0 = xr2[p][0], xo1 = xr2[p][1];
                f2 xn0 = __builtin_elementwise_fma(kID, xo0, s0);
                f2 xn1 = __builtin_elementwise_fma(kID, xo1, s1);
                xr2[p][0] = xn0; xr2[p][1] = xn1;
                f2 xt0 = __builtin_elementwise_fma(k15, xn0, xo0 * km05);
                f2 xt1 = __builtin_elementwise_fma(k15, xn1, xo1 * km05);
                if (!last) {
                    h4 nx = __builtin_bit_cast(h4,
                        make_uint2(pkrtz(xt0[0], xt0[1]),
                                   pkrtz(xt1[0], xt1[1])));
                    xt16[p] = nx;
                    *(h4*)&sXT16[bF] = nx;
                } else {
                    int li = u / UPR, uj = u - li * UPR;
                    int gi = gr0 + li;
                    if (li >= 10 && uj >= 3 && uj <= 18 && gi < M) {
                        *(float4*)&out[(size_t)gi * N + (gc0 + uj * 4)] =
                            make_float4(xt0[0], xt0[1], xt1[0], xt1[1]);
                    }
                }
            }
        }
    };

    primal(9, false);          // t=0 (dual(0) fused into init)
    __syncthreads();
    #pragma unroll 1
    for (int t = 1; t < 10; ++t) {
        int rem = 9 - t;
        dual(rem);
        __syncthreads();
        primal(rem, t == 9);
        __syncthreads();
    }
}

extern "C" void kernel_launch(void* const* d_in, const int* in_sizes, int n_in,
                              void* d_out, int out_size, void* d_ws, size_t ws_size,
                              hipStream_t stream)
{
    const float* img = (const float*)d_in[0];
    const float* w1  = (const float*)d_in[1];
    const float* w2  = (const float*)d_in[2];
    float* out = (float*)d_out;

    dim3 grid(N / TW, GY);   // 32 x 32 = 1024 blocks = 2/CU x 2 rounds
    pd_fused<<<grid, NT, 0, stream>>>(img, out, w1, w2);
}